// Round 12
// baseline (108.051 us; speedup 1.0000x reference)
//
#include <hip/hip_runtime.h>
#include <hip/hip_bf16.h>
#include <math.h>

// PersistentHomology: out = std(dist, ddof=1) / (mean(dist) + 1e-8) over the
// 8192x8192 Euclidean distance matrix of 8192 fp32 points, D=128.
// S1 = sum(dist) via bf16-MFMA Gram tiles (upper-triangle 256^2 blocks, r7
// structure = best measured). S2 closed form (exact fp64):
// 2N*sum|x_i|^2 - 2*|sum_i x_i|^2.
// Round 12: 2-kernel chain. Finalize fused into gram via last-block-done
// (atomic counter zeroed by prep; fixed-order reduction -> deterministic).

#define NPTS   8192
#define DIM    128
#define BT     256                            // block tile
#define NT2    (NPTS / BT)                    // 32 tiles per side
#define NBLK   (NT2 * (NT2 + 1) / 2)          // 528 upper-tri blocks
#define NPREP  (NPTS / 32)                    // 256 prep blocks
#define NTILES (NPTS / 128)                   // fp32 fallback path
#define NTOTSQ (NTILES * NTILES)

typedef __attribute__((ext_vector_type(8))) short short8;   // 8 bf16
typedef __attribute__((ext_vector_type(4))) float f32x4;    // MFMA accumulator

typedef const __attribute__((address_space(1))) void* gas_ptr;
typedef __attribute__((address_space(3))) void* las_ptr;

__device__ __forceinline__ void gload16(const void* g, void* l) {
    // DMA 16B/lane global->LDS; LDS dest = wave-uniform base + lane*16
    __builtin_amdgcn_global_load_lds((gas_ptr)g, (las_ptr)l, 16, 0, 0);
}
__device__ __forceinline__ float fsqrt(float x) {
    return __builtin_amdgcn_sqrtf(x);        // v_sqrt_f32
}

// ---- prep: fp32 -> bf16, fp32 norms, column-sum partials, zero counter ----
__global__ __launch_bounds__(256)
void ph_prep(const float* __restrict__ x, ushort* __restrict__ xb,
             float* __restrict__ sq, float* __restrict__ cs_part,
             unsigned int* __restrict__ counter)
{
    __shared__ float xs[32][129];                  // padded: conflict-free col reads
    const int tid = threadIdx.x;
    if (blockIdx.x == 0 && tid == 0) counter[0] = 0u;   // reset per call
    const int rw  = tid >> 3;                      // 0..31 row-in-block
    const int row = blockIdx.x * 32 + rw;
    const int seg = tid & 7;                       // 16 elems per thread
    const float4* p = reinterpret_cast<const float4*>(x + (size_t)row * DIM + seg * 16);
    float v[16];
    {
        float4 a = p[0], b = p[1], c = p[2], d = p[3];
        v[0]=a.x; v[1]=a.y; v[2]=a.z; v[3]=a.w;  v[4]=b.x; v[5]=b.y; v[6]=b.z; v[7]=b.w;
        v[8]=c.x; v[9]=c.y; v[10]=c.z; v[11]=c.w; v[12]=d.x; v[13]=d.y; v[14]=d.z; v[15]=d.w;
    }
    float s = 0.f;
    ushort h[16];
#pragma unroll
    for (int j = 0; j < 16; ++j) {
        __hip_bfloat16 hb = __float2bfloat16(v[j]);
        h[j] = *reinterpret_cast<ushort*>(&hb);
        s = fmaf(v[j], v[j], s);
        xs[rw][seg * 16 + j] = v[j];
    }
    short8 o0, o1;
#pragma unroll
    for (int j = 0; j < 8; ++j) { o0[j] = (short)h[j]; o1[j] = (short)h[j+8]; }
    short8* dst = reinterpret_cast<short8*>(xb + (size_t)row * DIM + seg * 16);
    dst[0] = o0; dst[1] = o1;
    s += __shfl_xor(s, 1); s += __shfl_xor(s, 2); s += __shfl_xor(s, 4);
    if (seg == 0) sq[row] = s;
    __syncthreads();
    if (tid < DIM) {                               // column sums over 32 rows
        float c = 0.f;
#pragma unroll 8
        for (int r = 0; r < 32; ++r) c += xs[r][tid];
        cs_part[blockIdx.x * DIM + tid] = c;
    }
}

// ---- main: r7 structure (256^2, 8 waves, dbuf 2-phase) + fused finalize ----
// LDS half-buffers: 256 rows x 128B, swizzled: phys = row*128 + (kb ^ ((row&7)<<4))
// Stage writes linear (gload_lds); inverse swizzle applied on the GLOBAL source.
__global__ __launch_bounds__(512)
void ph_gram(const ushort* __restrict__ xb, const float* __restrict__ sq,
             const float* __restrict__ cs_part, double* __restrict__ partials,
             unsigned int* __restrict__ counter, float* __restrict__ out)
{
    const int f   = blockIdx.x;          // 0..NBLK-1
    const int tid = threadIdx.x;

    // decode flat -> (bi, bj), bi <= bj ; T(r) = r*32 - r*(r-1)/2
    int bi = (int)((65.0f - fsqrt((float)(4225 - 8 * f))) * 0.5f);
    while ((bi + 1) * 32 - ((bi + 1) * bi) / 2 <= f) ++bi;
    while (bi * 32 - (bi * (bi - 1)) / 2 > f) --bi;
    const int bj = bi + (f - (bi * 32 - (bi * (bi - 1)) / 2));

    __shared__ ushort A0[BT * 64], B0[BT * 64];   // 32 KB each (K-half 0)
    __shared__ ushort A1[BT * 64], B1[BT * 64];   // 32 KB each (K-half 1)
    __shared__ double rr[16];
    __shared__ double red[512];
    __shared__ int    lastFlag;

    const int lane = tid & 63;
    const int wv   = tid >> 6;           // wave 0..7
    const int wr2  = wv >> 2;            // 0..1 -> row base *128
    const int wc4  = wv & 3;             // 0..3 -> col base *64

    const char* gA = (const char*)(xb + (size_t)bi * BT * DIM);
    const char* gB = (const char*)(xb + (size_t)bj * BT * DIM);

    // staging: waves 0-3 stage A (32 chunks of 1KB), waves 4-7 stage B
    const bool  stA  = wv < 4;
    const char* gsrc = stA ? gA : gB;
    const int   cb0  = (wv & 3) * 8;           // 8 chunks per wave
    const int   srow = lane >> 3;              // 0..7 within chunk
    const int   skb  = (lane & 7) * 16;        // 16B slot within 128B row

#define STAGE(h, dA, dB)                                                      \
    {                                                                         \
        char* dst_ = stA ? (char*)(dA) : (char*)(dB);                         \
        _Pragma("unroll")                                                     \
        for (int c = 0; c < 8; ++c) {                                         \
            const int chunk = cb0 + c;                                        \
            const int row   = chunk * 8 + srow;                               \
            const size_t go = (size_t)row * 256 + (h) * 128                   \
                              + (skb ^ ((row & 7) << 4));                     \
            gload16(gsrc + go, dst_ + chunk * 1024);                          \
        }                                                                     \
    }

    f32x4 acc[8][4];
#pragma unroll
    for (int m = 0; m < 8; ++m)
#pragma unroll
        for (int n = 0; n < 4; ++n) acc[m][n] = (f32x4){0.f, 0.f, 0.f, 0.f};

#define COMPUTE(dA, dB)                                                       \
    {                                                                         \
        _Pragma("unroll")                                                     \
        for (int ks = 0; ks < 2; ++ks) {                                      \
            const int kb = ks * 64 + (lane >> 4) * 16;                        \
            short8 af[8], bfr[4];                                             \
            _Pragma("unroll")                                                 \
            for (int m = 0; m < 8; ++m) {                                     \
                const int row = wr2 * 128 + m * 16 + (lane & 15);             \
                af[m] = *reinterpret_cast<const short8*>(                     \
                    (const char*)(dA) + row * 128 + (kb ^ ((row & 7) << 4))); \
            }                                                                 \
            _Pragma("unroll")                                                 \
            for (int n = 0; n < 4; ++n) {                                     \
                const int col = wc4 * 64 + n * 16 + (lane & 15);              \
                bfr[n] = *reinterpret_cast<const short8*>(                    \
                    (const char*)(dB) + col * 128 + (kb ^ ((col & 7) << 4))); \
            }                                                                 \
            _Pragma("unroll")                                                 \
            for (int m = 0; m < 8; ++m)                                       \
                _Pragma("unroll")                                             \
                for (int n = 0; n < 4; ++n)                                   \
                    acc[m][n] = __builtin_amdgcn_mfma_f32_16x16x32_bf16(      \
                        af[m], bfr[n], acc[m][n], 0, 0, 0);                   \
        }                                                                     \
    }

    STAGE(0, A0, B0);
    __syncthreads();      // half 0 ready (drains vmcnt)
    STAGE(1, A1, B1);     // half 1 flies under half-0 compute
    COMPUTE(A0, B0);
    __syncthreads();      // half 1 ready (loads landed under compute)
    COMPUTE(A1, B1);

    // ---- epilogue: S1 only (S2 closed-form), wave-uniform diag split ----
    const float* sqA = sq + bi * BT + wr2 * 128 + (lane >> 4) * 4;
    const float* sqB = sq + bj * BT + wc4 * 64 + (lane & 15);
    float nb[4];
#pragma unroll
    for (int n = 0; n < 4; ++n) nb[n] = sqB[n * 16];

    float s1a = 0.f, s1b = 0.f, s1c = 0.f, s1d = 0.f;
    const bool diag = (bi == bj);
    if (!diag) {
#pragma unroll
        for (int m = 0; m < 8; ++m) {
            const float4 v = *reinterpret_cast<const float4*>(sqA + m * 16);
#pragma unroll
            for (int n = 0; n < 4; ++n) {
                s1a += fsqrt(fmaxf(fmaf(-2.f, acc[m][n][0], v.x + nb[n]), 0.f));
                s1b += fsqrt(fmaxf(fmaf(-2.f, acc[m][n][1], v.y + nb[n]), 0.f));
                s1c += fsqrt(fmaxf(fmaf(-2.f, acc[m][n][2], v.z + nb[n]), 0.f));
                s1d += fsqrt(fmaxf(fmaf(-2.f, acc[m][n][3], v.w + nb[n]), 0.f));
            }
        }
    } else {
#pragma unroll
        for (int m = 0; m < 8; ++m) {
            const float4 v = *reinterpret_cast<const float4*>(sqA + m * 16);
            const float nav[4] = {v.x, v.y, v.z, v.w};
#pragma unroll
            for (int n = 0; n < 4; ++n) {
                const int col = wc4 * 64 + n * 16 + (lane & 15);
#pragma unroll
                for (int r = 0; r < 4; ++r) {
                    const int row = wr2 * 128 + m * 16 + (lane >> 4) * 4 + r;
                    float d = fmaxf(fmaf(-2.f, acc[m][n][r], nav[r] + nb[n]), 0.f);
                    if (row == col) d = 0.f;      // exact-0 diagonal like ref
                    s1a += fsqrt(d);
                }
            }
        }
    }
    float s1 = (s1a + s1b) + (s1c + s1d);
#pragma unroll
    for (int off = 1; off < 64; off <<= 1) s1 += __shfl_xor(s1, off);
    const double w = diag ? 1.0 : 2.0;
    if (lane == 0) rr[wv] = (double)s1 * w;
    __syncthreads();
    if (tid == 0) {
        double t1 = 0.0;
#pragma unroll
        for (int i = 0; i < 8; ++i) t1 += rr[i];
        partials[f] = t1;
    }

    // ---- last-block-done fused finalize (deterministic fixed-order reduce) ----
    __threadfence();                       // publish partials[f] (release)
    if (tid == 0) {
        unsigned int prev = atomicAdd(counter, 1u);
        lastFlag = (prev == (unsigned int)(NBLK - 1));
    }
    __syncthreads();
    if (!lastFlag) return;
    __threadfence();                       // acquire: all partials visible

    // S1 over 528 block partials
    double t = 0.0;
    for (int i = tid; i < NBLK; i += 512) t += partials[i];
    red[tid] = t; __syncthreads();
    for (int off = 256; off > 0; off >>= 1) {
        if (tid < off) red[tid] += red[tid + off];
        __syncthreads();
    }
    const double S1 = red[0];
    __syncthreads();

    // sum of squared norms
    t = 0.0;
    for (int i = tid; i < NPTS; i += 512) t += (double)sq[i];
    red[tid] = t; __syncthreads();
    for (int off = 256; off > 0; off >>= 1) {
        if (tid < off) red[tid] += red[tid + off];
        __syncthreads();
    }
    const double SN = red[0];
    __syncthreads();

    // |sum_i x_i|^2 from per-prep-block column sums
    t = 0.0;
    if (tid < DIM) {
        double c = 0.0;
        for (int b = 0; b < NPREP; ++b) c += (double)cs_part[b * DIM + tid];
        t = c * c;
    }
    red[tid] = t; __syncthreads();
    for (int off = 256; off > 0; off >>= 1) {
        if (tid < off) red[tid] += red[tid + off];
        __syncthreads();
    }
    if (tid == 0) {
        const double M    = (double)NPTS * (double)NPTS;
        const double S2   = 2.0 * (double)NPTS * SN - 2.0 * red[0];
        const double mean = S1 / M;
        double var = (S2 - S1 * S1 / M) / (M - 1.0);
        if (var < 0.0) var = 0.0;
        out[0] = (float)(sqrt(var) / (mean + 1e-8));
    }
#undef STAGE
#undef COMPUTE
}

// ---------------- fp32 fallback (only if ws too small) ----------------
#define LSTR 132
__global__ __launch_bounds__(256)
void ph_pair_kernel(const float* __restrict__ x, double* __restrict__ partials)
{
    const int bi  = blockIdx.y;
    const int bj  = blockIdx.x;
    const int tid = threadIdx.x;
    const int flat = bi * NTILES + bj;
    if (bj < bi) {
        if (tid == 0) { partials[2*flat] = 0.0; partials[2*flat+1] = 0.0; }
        return;
    }
    __shared__ __align__(16) float As[128 * LSTR];
    __shared__ __align__(16) float Bs[128 * LSTR];
    __shared__ float  nA[128];
    __shared__ float  nB[128];
    __shared__ double red1[256];
    __shared__ double red2[256];
    const float* Ab = x + (size_t)bi * 128 * DIM;
    const float* Bb = x + (size_t)bj * 128 * DIM;
#pragma unroll
    for (int it = 0; it < 16; ++it) {
        const int e   = (tid + it * 256) * 4;
        const int row = e >> 7;
        const int k   = e & 127;
        float4 va = *reinterpret_cast<const float4*>(Ab + e);
        As[(k+0)*LSTR + row] = va.x; As[(k+1)*LSTR + row] = va.y;
        As[(k+2)*LSTR + row] = va.z; As[(k+3)*LSTR + row] = va.w;
        float4 vb = *reinterpret_cast<const float4*>(Bb + e);
        Bs[(k+0)*LSTR + row] = vb.x; Bs[(k+1)*LSTR + row] = vb.y;
        Bs[(k+2)*LSTR + row] = vb.z; Bs[(k+3)*LSTR + row] = vb.w;
    }
    __syncthreads();
    if (tid < 128) {
        float s = 0.f;
#pragma unroll 8
        for (int k = 0; k < DIM; ++k) { float v = As[k*LSTR + tid]; s = fmaf(v, v, s); }
        nA[tid] = s;
    } else {
        const int r = tid - 128;
        float s = 0.f;
#pragma unroll 8
        for (int k = 0; k < DIM; ++k) { float v = Bs[k*LSTR + r]; s = fmaf(v, v, s); }
        nB[r] = s;
    }
    __syncthreads();
    const int tx = tid & 15, ty = tid >> 4;
    const int ra = ty * 8, cb = tx * 8;
    float acc[8][8];
#pragma unroll
    for (int r = 0; r < 8; ++r)
#pragma unroll
        for (int c = 0; c < 8; ++c) acc[r][c] = 0.f;
#pragma unroll 4
    for (int k = 0; k < DIM; ++k) {
        const float4 a0 = *reinterpret_cast<const float4*>(&As[k*LSTR + ra]);
        const float4 a1 = *reinterpret_cast<const float4*>(&As[k*LSTR + ra + 4]);
        const float4 b0 = *reinterpret_cast<const float4*>(&Bs[k*LSTR + cb]);
        const float4 b1 = *reinterpret_cast<const float4*>(&Bs[k*LSTR + cb + 4]);
        const float a[8] = {a0.x,a0.y,a0.z,a0.w,a1.x,a1.y,a1.z,a1.w};
        const float b[8] = {b0.x,b0.y,b0.z,b0.w,b1.x,b1.y,b1.z,b1.w};
#pragma unroll
        for (int r = 0; r < 8; ++r)
#pragma unroll
            for (int c = 0; c < 8; ++c)
                acc[r][c] = fmaf(a[r], b[c], acc[r][c]);
    }
    double s1 = 0.0, s2 = 0.0;
    const int gi0 = bi*128 + ra, gj0 = bj*128 + cb;
#pragma unroll
    for (int r = 0; r < 8; ++r) {
#pragma unroll
        for (int c = 0; c < 8; ++c) {
            float d2 = nA[ra+r] + nB[cb+c] - 2.0f * acc[r][c];
            d2 = fmaxf(d2, 0.0f);
            if (gi0 + r == gj0 + c) d2 = 0.0f;
            s1 += (double)sqrtf(d2);
            s2 += (double)d2;
        }
    }
    const double w = (bi == bj) ? 1.0 : 2.0;
    s1 *= w; s2 *= w;
    red1[tid] = s1; red2[tid] = s2;
    __syncthreads();
    for (int off = 128; off > 0; off >>= 1) {
        if (tid < off) { red1[tid] += red1[tid+off]; red2[tid] += red2[tid+off]; }
        __syncthreads();
    }
    if (tid == 0) { partials[2*flat] = red1[0]; partials[2*flat+1] = red2[0]; }
}

__global__ __launch_bounds__(256)
void ph_finalize_sq(const double* __restrict__ partials, float* __restrict__ out)
{
    __shared__ double r1[256], r2[256];
    const int tid = threadIdx.x;
    double s1 = 0.0, s2 = 0.0;
    for (int i = tid; i < NTOTSQ; i += 256) { s1 += partials[2*i]; s2 += partials[2*i+1]; }
    r1[tid] = s1; r2[tid] = s2;
    __syncthreads();
    for (int off = 128; off > 0; off >>= 1) {
        if (tid < off) { r1[tid] += r1[tid+off]; r2[tid] += r2[tid+off]; }
        __syncthreads();
    }
    if (tid == 0) {
        const double M    = (double)NPTS * (double)NPTS;
        const double mean = r1[0] / M;
        double var = (r2[0] - r1[0]*r1[0]/M) / (M - 1.0);
        if (var < 0.0) var = 0.0;
        out[0] = (float)(sqrt(var) / (mean + 1e-8));
    }
}

extern "C" void kernel_launch(void* const* d_in, const int* in_sizes, int n_in,
                              void* d_out, int out_size, void* d_ws, size_t ws_size,
                              hipStream_t stream)
{
    const float* x = (const float*)d_in[0];   // [8192, 128] fp32
    float* out     = (float*)d_out;

    // ws: xb bf16 (2MB) | sq (32KB) | cs_part (128KB) | partials (528*8) | counter
    const size_t XB_OFF = 0;
    const size_t SQ_OFF = (size_t)NPTS * DIM * sizeof(ushort);   // 2 MB
    const size_t CS_OFF = SQ_OFF + NPTS * sizeof(float);
    const size_t PT_OFF = CS_OFF + (size_t)NPREP * DIM * sizeof(float);
    const size_t CT_OFF = PT_OFF + (size_t)NBLK * sizeof(double);
    const size_t NEEDED = CT_OFF + sizeof(unsigned int);

    if (ws_size >= NEEDED) {
        ushort*       xb       = (ushort*)      ((char*)d_ws + XB_OFF);
        float*        sq       = (float*)       ((char*)d_ws + SQ_OFF);
        float*        cs_part  = (float*)       ((char*)d_ws + CS_OFF);
        double*       partials = (double*)      ((char*)d_ws + PT_OFF);
        unsigned int* counter  = (unsigned int*)((char*)d_ws + CT_OFF);

        ph_prep<<<NPREP, 256, 0, stream>>>(x, xb, sq, cs_part, counter);
        ph_gram<<<NBLK, 512, 0, stream>>>(xb, sq, cs_part, partials, counter, out);
    } else {
        double* partials = (double*)d_ws;
        ph_pair_kernel<<<dim3(NTILES, NTILES), 256, 0, stream>>>(x, partials);
        ph_finalize_sq<<<1, 256, 0, stream>>>(partials, out);
    }
}

// Round 13
// 38.499 us; speedup vs baseline: 2.8066x; 2.8066x over previous
//
#include <hip/hip_runtime.h>
#include <hip/hip_bf16.h>
#include <math.h>

// PersistentHomology: out = std(dist, ddof=1) / (mean(dist) + 1e-8) over the
// 8192x8192 Euclidean distance matrix of 8192 fp32 points, D=128.
// S1 = sum(dist) via bf16-MFMA Gram tiles (upper-triangle 256^2 blocks, r7
// structure = best of 7 measured variants). S2 closed form (exact fp64):
// 2N*sum|x_i|^2 - 2*|sum_i x_i|^2.
// Round 13: r7 gram + S1-only epilogue + separate 1-block finalize.
// (r12 lesson: device-scope fences per block -> cross-XCD L2 writeback
//  serialization, 3x regression. Keep the 3-kernel chain.)

#define NPTS   8192
#define DIM    128
#define BT     256                            // block tile
#define NT2    (NPTS / BT)                    // 32 tiles per side
#define NBLK   (NT2 * (NT2 + 1) / 2)          // 528 upper-tri blocks
#define NPREP  (NPTS / 32)                    // 256 prep blocks
#define NTILES (NPTS / 128)                   // fp32 fallback path
#define NTOTSQ (NTILES * NTILES)

typedef __attribute__((ext_vector_type(8))) short short8;   // 8 bf16
typedef __attribute__((ext_vector_type(4))) float f32x4;    // MFMA accumulator

typedef const __attribute__((address_space(1))) void* gas_ptr;
typedef __attribute__((address_space(3))) void* las_ptr;

__device__ __forceinline__ void gload16(const void* g, void* l) {
    // DMA 16B/lane global->LDS; LDS dest = wave-uniform base + lane*16
    __builtin_amdgcn_global_load_lds((gas_ptr)g, (las_ptr)l, 16, 0, 0);
}
__device__ __forceinline__ float fsqrt(float x) {
    return __builtin_amdgcn_sqrtf(x);        // v_sqrt_f32
}

// ---- prep: fp32 -> bf16, fp32 norms, per-block fp32 column-sum partials ----
__global__ __launch_bounds__(256)
void ph_prep(const float* __restrict__ x, ushort* __restrict__ xb,
             float* __restrict__ sq, float* __restrict__ cs_part)
{
    __shared__ float xs[32][129];                  // padded: conflict-free col reads
    const int tid = threadIdx.x;
    const int rw  = tid >> 3;                      // 0..31 row-in-block
    const int row = blockIdx.x * 32 + rw;
    const int seg = tid & 7;                       // 16 elems per thread
    const float4* p = reinterpret_cast<const float4*>(x + (size_t)row * DIM + seg * 16);
    float v[16];
    {
        float4 a = p[0], b = p[1], c = p[2], d = p[3];
        v[0]=a.x; v[1]=a.y; v[2]=a.z; v[3]=a.w;  v[4]=b.x; v[5]=b.y; v[6]=b.z; v[7]=b.w;
        v[8]=c.x; v[9]=c.y; v[10]=c.z; v[11]=c.w; v[12]=d.x; v[13]=d.y; v[14]=d.z; v[15]=d.w;
    }
    float s = 0.f;
    ushort h[16];
#pragma unroll
    for (int j = 0; j < 16; ++j) {
        __hip_bfloat16 hb = __float2bfloat16(v[j]);
        h[j] = *reinterpret_cast<ushort*>(&hb);
        s = fmaf(v[j], v[j], s);
        xs[rw][seg * 16 + j] = v[j];
    }
    short8 o0, o1;
#pragma unroll
    for (int j = 0; j < 8; ++j) { o0[j] = (short)h[j]; o1[j] = (short)h[j+8]; }
    short8* dst = reinterpret_cast<short8*>(xb + (size_t)row * DIM + seg * 16);
    dst[0] = o0; dst[1] = o1;
    s += __shfl_xor(s, 1); s += __shfl_xor(s, 2); s += __shfl_xor(s, 4);
    if (seg == 0) sq[row] = s;
    __syncthreads();
    if (tid < DIM) {                               // column sums over 32 rows
        float c = 0.f;
#pragma unroll 8
        for (int r = 0; r < 32; ++r) c += xs[r][tid];
        cs_part[blockIdx.x * DIM + tid] = c;
    }
}

// ---- main: r7 structure (256^2, 8 waves, dbuf 2-phase), S1-only epilogue ----
// LDS half-buffers: 256 rows x 128B, swizzled: phys = row*128 + (kb ^ ((row&7)<<4))
// Stage writes linear (gload_lds); inverse swizzle applied on the GLOBAL source.
__global__ __launch_bounds__(512)
void ph_gram(const ushort* __restrict__ xb, const float* __restrict__ sq,
             double* __restrict__ partials)
{
    const int f   = blockIdx.x;          // 0..NBLK-1
    const int tid = threadIdx.x;

    // decode flat -> (bi, bj), bi <= bj ; T(r) = r*32 - r*(r-1)/2
    int bi = (int)((65.0f - fsqrt((float)(4225 - 8 * f))) * 0.5f);
    while ((bi + 1) * 32 - ((bi + 1) * bi) / 2 <= f) ++bi;
    while (bi * 32 - (bi * (bi - 1)) / 2 > f) --bi;
    const int bj = bi + (f - (bi * 32 - (bi * (bi - 1)) / 2));

    __shared__ ushort A0[BT * 64], B0[BT * 64];   // 32 KB each (K-half 0)
    __shared__ ushort A1[BT * 64], B1[BT * 64];   // 32 KB each (K-half 1)
    __shared__ double rr[8];

    const int lane = tid & 63;
    const int wv   = tid >> 6;           // wave 0..7
    const int wr2  = wv >> 2;            // 0..1 -> row base *128
    const int wc4  = wv & 3;             // 0..3 -> col base *64

    const char* gA = (const char*)(xb + (size_t)bi * BT * DIM);
    const char* gB = (const char*)(xb + (size_t)bj * BT * DIM);

    // staging: waves 0-3 stage A (32 chunks of 1KB), waves 4-7 stage B
    const bool  stA  = wv < 4;
    const char* gsrc = stA ? gA : gB;
    const int   cb0  = (wv & 3) * 8;           // 8 chunks per wave
    const int   srow = lane >> 3;              // 0..7 within chunk
    const int   skb  = (lane & 7) * 16;        // 16B slot within 128B row

#define STAGE(h, dA, dB)                                                      \
    {                                                                         \
        char* dst_ = stA ? (char*)(dA) : (char*)(dB);                         \
        _Pragma("unroll")                                                     \
        for (int c = 0; c < 8; ++c) {                                         \
            const int chunk = cb0 + c;                                        \
            const int row   = chunk * 8 + srow;                               \
            const size_t go = (size_t)row * 256 + (h) * 128                   \
                              + (skb ^ ((row & 7) << 4));                     \
            gload16(gsrc + go, dst_ + chunk * 1024);                          \
        }                                                                     \
    }

    f32x4 acc[8][4];
#pragma unroll
    for (int m = 0; m < 8; ++m)
#pragma unroll
        for (int n = 0; n < 4; ++n) acc[m][n] = (f32x4){0.f, 0.f, 0.f, 0.f};

#define COMPUTE(dA, dB)                                                       \
    {                                                                         \
        _Pragma("unroll")                                                     \
        for (int ks = 0; ks < 2; ++ks) {                                      \
            const int kb = ks * 64 + (lane >> 4) * 16;                        \
            short8 af[8], bfr[4];                                             \
            _Pragma("unroll")                                                 \
            for (int m = 0; m < 8; ++m) {                                     \
                const int row = wr2 * 128 + m * 16 + (lane & 15);             \
                af[m] = *reinterpret_cast<const short8*>(                     \
                    (const char*)(dA) + row * 128 + (kb ^ ((row & 7) << 4))); \
            }                                                                 \
            _Pragma("unroll")                                                 \
            for (int n = 0; n < 4; ++n) {                                     \
                const int col = wc4 * 64 + n * 16 + (lane & 15);              \
                bfr[n] = *reinterpret_cast<const short8*>(                    \
                    (const char*)(dB) + col * 128 + (kb ^ ((col & 7) << 4))); \
            }                                                                 \
            _Pragma("unroll")                                                 \
            for (int m = 0; m < 8; ++m)                                       \
                _Pragma("unroll")                                             \
                for (int n = 0; n < 4; ++n)                                   \
                    acc[m][n] = __builtin_amdgcn_mfma_f32_16x16x32_bf16(      \
                        af[m], bfr[n], acc[m][n], 0, 0, 0);                   \
        }                                                                     \
    }

    STAGE(0, A0, B0);
    __syncthreads();      // half 0 ready (drains vmcnt)
    STAGE(1, A1, B1);     // half 1 flies under half-0 compute
    COMPUTE(A0, B0);
    __syncthreads();      // half 1 ready (loads landed under compute)
    COMPUTE(A1, B1);

    // ---- epilogue: S1 only (S2 closed-form), wave-uniform diag split ----
    const float* sqA = sq + bi * BT + wr2 * 128 + (lane >> 4) * 4;
    const float* sqB = sq + bj * BT + wc4 * 64 + (lane & 15);
    float nb[4];
#pragma unroll
    for (int n = 0; n < 4; ++n) nb[n] = sqB[n * 16];

    float s1a = 0.f, s1b = 0.f, s1c = 0.f, s1d = 0.f;
    const bool diag = (bi == bj);
    if (!diag) {
#pragma unroll
        for (int m = 0; m < 8; ++m) {
            const float4 v = *reinterpret_cast<const float4*>(sqA + m * 16);
#pragma unroll
            for (int n = 0; n < 4; ++n) {
                s1a += fsqrt(fmaxf(fmaf(-2.f, acc[m][n][0], v.x + nb[n]), 0.f));
                s1b += fsqrt(fmaxf(fmaf(-2.f, acc[m][n][1], v.y + nb[n]), 0.f));
                s1c += fsqrt(fmaxf(fmaf(-2.f, acc[m][n][2], v.z + nb[n]), 0.f));
                s1d += fsqrt(fmaxf(fmaf(-2.f, acc[m][n][3], v.w + nb[n]), 0.f));
            }
        }
    } else {
#pragma unroll
        for (int m = 0; m < 8; ++m) {
            const float4 v = *reinterpret_cast<const float4*>(sqA + m * 16);
            const float nav[4] = {v.x, v.y, v.z, v.w};
#pragma unroll
            for (int n = 0; n < 4; ++n) {
                const int col = wc4 * 64 + n * 16 + (lane & 15);
#pragma unroll
                for (int r = 0; r < 4; ++r) {
                    const int row = wr2 * 128 + m * 16 + (lane >> 4) * 4 + r;
                    float d = fmaxf(fmaf(-2.f, acc[m][n][r], nav[r] + nb[n]), 0.f);
                    if (row == col) d = 0.f;      // exact-0 diagonal like ref
                    s1a += fsqrt(d);
                }
            }
        }
    }
    float s1 = (s1a + s1b) + (s1c + s1d);
#pragma unroll
    for (int off = 1; off < 64; off <<= 1) s1 += __shfl_xor(s1, off);
    const double w = diag ? 1.0 : 2.0;
    if (lane == 0) rr[wv] = (double)s1 * w;
    __syncthreads();
    if (tid == 0) {
        double t1 = 0.0;
#pragma unroll
        for (int i = 0; i < 8; ++i) t1 += rr[i];
        partials[f] = t1;
    }
#undef STAGE
#undef COMPUTE
}

// ---- finalize: S1 reduce + closed-form S2 (deterministic fp64) ----
__global__ __launch_bounds__(256)
void ph_finalize(const double* __restrict__ partials, const float* __restrict__ sq,
                 const float* __restrict__ cs_part, float* __restrict__ out)
{
    __shared__ double r1[256], r2[256], r3[128];
    const int tid = threadIdx.x;
    double s1 = 0.0;
    for (int i = tid; i < NBLK; i += 256) s1 += partials[i];
    double sn = 0.0;
    for (int k = 0; k < NPTS / 256; ++k) sn += (double)sq[tid + k * 256];
    r1[tid] = s1; r2[tid] = sn;
    if (tid < DIM) {                       // column sum over 256 prep blocks
        double c = 0.0;
        for (int b = 0; b < NPREP; ++b) c += (double)cs_part[b * DIM + tid];
        r3[tid] = c * c;                   // squared component
    }
    __syncthreads();
    for (int off = 128; off > 0; off >>= 1) {
        if (tid < off) { r1[tid] += r1[tid + off]; r2[tid] += r2[tid + off]; }
        __syncthreads();
    }
    for (int off = 64; off > 0; off >>= 1) {
        if (tid < off) r3[tid] += r3[tid + off];
        __syncthreads();
    }
    if (tid == 0) {
        const double M    = (double)NPTS * (double)NPTS;
        const double S1   = r1[0];
        const double S2   = 2.0 * (double)NPTS * r2[0] - 2.0 * r3[0];
        const double mean = S1 / M;
        double var = (S2 - S1 * S1 / M) / (M - 1.0);
        if (var < 0.0) var = 0.0;
        out[0] = (float)(sqrt(var) / (mean + 1e-8));
    }
}

// ---------------- fp32 fallback (only if ws too small) ----------------
#define LSTR 132
__global__ __launch_bounds__(256)
void ph_pair_kernel(const float* __restrict__ x, double* __restrict__ partials)
{
    const int bi  = blockIdx.y;
    const int bj  = blockIdx.x;
    const int tid = threadIdx.x;
    const int flat = bi * NTILES + bj;
    if (bj < bi) {
        if (tid == 0) { partials[2*flat] = 0.0; partials[2*flat+1] = 0.0; }
        return;
    }
    __shared__ __align__(16) float As[128 * LSTR];
    __shared__ __align__(16) float Bs[128 * LSTR];
    __shared__ float  nA[128];
    __shared__ float  nB[128];
    __shared__ double red1[256];
    __shared__ double red2[256];
    const float* Ab = x + (size_t)bi * 128 * DIM;
    const float* Bb = x + (size_t)bj * 128 * DIM;
#pragma unroll
    for (int it = 0; it < 16; ++it) {
        const int e   = (tid + it * 256) * 4;
        const int row = e >> 7;
        const int k   = e & 127;
        float4 va = *reinterpret_cast<const float4*>(Ab + e);
        As[(k+0)*LSTR + row] = va.x; As[(k+1)*LSTR + row] = va.y;
        As[(k+2)*LSTR + row] = va.z; As[(k+3)*LSTR + row] = va.w;
        float4 vb = *reinterpret_cast<const float4*>(Bb + e);
        Bs[(k+0)*LSTR + row] = vb.x; Bs[(k+1)*LSTR + row] = vb.y;
        Bs[(k+2)*LSTR + row] = vb.z; Bs[(k+3)*LSTR + row] = vb.w;
    }
    __syncthreads();
    if (tid < 128) {
        float s = 0.f;
#pragma unroll 8
        for (int k = 0; k < DIM; ++k) { float v = As[k*LSTR + tid]; s = fmaf(v, v, s); }
        nA[tid] = s;
    } else {
        const int r = tid - 128;
        float s = 0.f;
#pragma unroll 8
        for (int k = 0; k < DIM; ++k) { float v = Bs[k*LSTR + r]; s = fmaf(v, v, s); }
        nB[r] = s;
    }
    __syncthreads();
    const int tx = tid & 15, ty = tid >> 4;
    const int ra = ty * 8, cb = tx * 8;
    float acc[8][8];
#pragma unroll
    for (int r = 0; r < 8; ++r)
#pragma unroll
        for (int c = 0; c < 8; ++c) acc[r][c] = 0.f;
#pragma unroll 4
    for (int k = 0; k < DIM; ++k) {
        const float4 a0 = *reinterpret_cast<const float4*>(&As[k*LSTR + ra]);
        const float4 a1 = *reinterpret_cast<const float4*>(&As[k*LSTR + ra + 4]);
        const float4 b0 = *reinterpret_cast<const float4*>(&Bs[k*LSTR + cb]);
        const float4 b1 = *reinterpret_cast<const float4*>(&Bs[k*LSTR + cb + 4]);
        const float a[8] = {a0.x,a0.y,a0.z,a0.w,a1.x,a1.y,a1.z,a1.w};
        const float b[8] = {b0.x,b0.y,b0.z,b0.w,b1.x,b1.y,b1.z,b1.w};
#pragma unroll
        for (int r = 0; r < 8; ++r)
#pragma unroll
            for (int c = 0; c < 8; ++c)
                acc[r][c] = fmaf(a[r], b[c], acc[r][c]);
    }
    double s1 = 0.0, s2 = 0.0;
    const int gi0 = bi*128 + ra, gj0 = bj*128 + cb;
#pragma unroll
    for (int r = 0; r < 8; ++r) {
#pragma unroll
        for (int c = 0; c < 8; ++c) {
            float d2 = nA[ra+r] + nB[cb+c] - 2.0f * acc[r][c];
            d2 = fmaxf(d2, 0.0f);
            if (gi0 + r == gj0 + c) d2 = 0.0f;
            s1 += (double)sqrtf(d2);
            s2 += (double)d2;
        }
    }
    const double w = (bi == bj) ? 1.0 : 2.0;
    s1 *= w; s2 *= w;
    red1[tid] = s1; red2[tid] = s2;
    __syncthreads();
    for (int off = 128; off > 0; off >>= 1) {
        if (tid < off) { red1[tid] += red1[tid+off]; red2[tid] += red2[tid+off]; }
        __syncthreads();
    }
    if (tid == 0) { partials[2*flat] = red1[0]; partials[2*flat+1] = red2[0]; }
}

__global__ __launch_bounds__(256)
void ph_finalize_sq(const double* __restrict__ partials, float* __restrict__ out)
{
    __shared__ double r1[256], r2[256];
    const int tid = threadIdx.x;
    double s1 = 0.0, s2 = 0.0;
    for (int i = tid; i < NTOTSQ; i += 256) { s1 += partials[2*i]; s2 += partials[2*i+1]; }
    r1[tid] = s1; r2[tid] = s2;
    __syncthreads();
    for (int off = 128; off > 0; off >>= 1) {
        if (tid < off) { r1[tid] += r1[tid+off]; r2[tid] += r2[tid+off]; }
        __syncthreads();
    }
    if (tid == 0) {
        const double M    = (double)NPTS * (double)NPTS;
        const double mean = r1[0] / M;
        double var = (r2[0] - r1[0]*r1[0]/M) / (M - 1.0);
        if (var < 0.0) var = 0.0;
        out[0] = (float)(sqrt(var) / (mean + 1e-8));
    }
}

extern "C" void kernel_launch(void* const* d_in, const int* in_sizes, int n_in,
                              void* d_out, int out_size, void* d_ws, size_t ws_size,
                              hipStream_t stream)
{
    const float* x = (const float*)d_in[0];   // [8192, 128] fp32
    float* out     = (float*)d_out;

    // ws layout: xb bf16 (2MB) | sq (32KB) | cs_part (128KB) | partials (528*8)
    const size_t XB_OFF = 0;
    const size_t SQ_OFF = (size_t)NPTS * DIM * sizeof(ushort);   // 2 MB
    const size_t CS_OFF = SQ_OFF + NPTS * sizeof(float);
    const size_t PT_OFF = CS_OFF + (size_t)NPREP * DIM * sizeof(float);
    const size_t NEEDED = PT_OFF + (size_t)NBLK * sizeof(double);

    if (ws_size >= NEEDED) {
        ushort* xb       = (ushort*)((char*)d_ws + XB_OFF);
        float*  sq       = (float*) ((char*)d_ws + SQ_OFF);
        float*  cs_part  = (float*) ((char*)d_ws + CS_OFF);
        double* partials = (double*)((char*)d_ws + PT_OFF);

        ph_prep<<<NPREP, 256, 0, stream>>>(x, xb, sq, cs_part);
        ph_gram<<<NBLK, 512, 0, stream>>>(xb, sq, partials);
        ph_finalize<<<1, 256, 0, stream>>>(partials, sq, cs_part, out);
    } else {
        double* partials = (double*)d_ws;
        ph_pair_kernel<<<dim3(NTILES, NTILES), 256, 0, stream>>>(x, partials);
        ph_finalize_sq<<<1, 256, 0, stream>>>(partials, out);
    }
}

// Round 14
// 37.058 us; speedup vs baseline: 2.9157x; 1.0389x over previous
//
#include <hip/hip_runtime.h>
#include <hip/hip_bf16.h>
#include <math.h>

// PersistentHomology: out = std(dist, ddof=1) / (mean(dist) + 1e-8) over the
// 8192x8192 Euclidean distance matrix of 8192 fp32 points, D=128.
// Gram trick: dist^2 = |xi|^2 + |xj|^2 - 2 xi.xj ; S1,S2 summed in-block
// (r7-proven dual-sum epilogue; r13 showed closed-form-S2 + serial finalize
// is a net loss). bf16 MFMA Gram (random +-3e-3 per-dist error averages out;
// measured absmax 0 every round). Norms exact fp32.
// Round 14: 256 blocks x 2-3 pairs. A-tile (64KB) persistent in LDS across a
// block's pairs; only B streams (64KB/pair) through r7's exact double-buffered
// 2-sync pipeline with cross-pair prefetch. Zero dispatch tail (1 block/CU).

#define NPTS   8192
#define DIM    128
#define BT     256                            // block tile
#define NT2    (NPTS / BT)                    // 32 tiles per side
#define NPAIR  (NT2 * (NT2 + 1) / 2)          // 528 upper-tri pairs
#define NGBLK  256                            // 16 blocks x3 pairs + 240 x2
#define NPREP  (NPTS / 32)                    // 256 prep blocks
#define NTILES (NPTS / 128)                   // fp32 fallback path
#define NTOTSQ (NTILES * NTILES)

typedef __attribute__((ext_vector_type(8))) short short8;   // 8 bf16
typedef __attribute__((ext_vector_type(4))) float f32x4;    // MFMA accumulator

typedef const __attribute__((address_space(1))) void* gas_ptr;
typedef __attribute__((address_space(3))) void* las_ptr;

__device__ __forceinline__ void gload16(const void* g, void* l) {
    // DMA 16B/lane global->LDS; LDS dest = wave-uniform base + lane*16
    __builtin_amdgcn_global_load_lds((gas_ptr)g, (las_ptr)l, 16, 0, 0);
}
__device__ __forceinline__ float fsqrt(float x) {
    return __builtin_amdgcn_sqrtf(x);        // v_sqrt_f32
}

// ---------------- prep: fp32 -> bf16 + fp32 squared norms (fused, r7) --------
__global__ __launch_bounds__(256)
void ph_prep(const float* __restrict__ x, ushort* __restrict__ xb,
             float* __restrict__ sq)
{
    const int tid = threadIdx.x;
    const int row = blockIdx.x * 32 + (tid >> 3);
    const int seg = tid & 7;                       // 16 elems per thread
    const float4* p = reinterpret_cast<const float4*>(x + (size_t)row * DIM + seg * 16);
    float v[16];
    {
        float4 a = p[0], b = p[1], c = p[2], d = p[3];
        v[0]=a.x; v[1]=a.y; v[2]=a.z; v[3]=a.w;  v[4]=b.x; v[5]=b.y; v[6]=b.z; v[7]=b.w;
        v[8]=c.x; v[9]=c.y; v[10]=c.z; v[11]=c.w; v[12]=d.x; v[13]=d.y; v[14]=d.z; v[15]=d.w;
    }
    float s = 0.f;
    ushort h[16];
#pragma unroll
    for (int j = 0; j < 16; ++j) {
        __hip_bfloat16 hb = __float2bfloat16(v[j]);
        h[j] = *reinterpret_cast<ushort*>(&hb);
        s = fmaf(v[j], v[j], s);
    }
    short8 o0, o1;
#pragma unroll
    for (int j = 0; j < 8; ++j) { o0[j] = (short)h[j]; o1[j] = (short)h[j+8]; }
    short8* dst = reinterpret_cast<short8*>(xb + (size_t)row * DIM + seg * 16);
    dst[0] = o0; dst[1] = o1;
    s += __shfl_xor(s, 1); s += __shfl_xor(s, 2); s += __shfl_xor(s, 4);
    if (seg == 0) sq[row] = s;
}

// ---- main: 256^2 tiles, 8 waves, persistent-A + streamed-B (r7 schedule) ----
// LDS half-buffers: 256 rows x 128B, swizzled: phys = row*128 + (kb ^ ((row&7)<<4))
// Stage writes linear (gload_lds); inverse swizzle applied on the GLOBAL source.
__global__ __launch_bounds__(512)
void ph_gram(const ushort* __restrict__ xb, const float* __restrict__ sq,
             double* __restrict__ partials)
{
    const int b   = blockIdx.x;          // 0..NGBLK-1
    const int tid = threadIdx.x;

    // pair range: 528 = 16*3 + 240*2, contiguous row-major order
    const int pstart = (b < 16) ? 3 * b : 48 + 2 * (b - 16);
    const int pcnt   = (b < 16) ? 3 : 2;

    // decode pstart -> (si, tj), si <= tj ; T(r) = r*32 - r*(r-1)/2
    int si = (int)((65.0f - fsqrt((float)(4225 - 8 * pstart))) * 0.5f);
    while ((si + 1) * 32 - ((si + 1) * si) / 2 <= pstart) ++si;
    while (si * 32 - (si * (si - 1)) / 2 > pstart) --si;
    int tj = si + (pstart - (si * 32 - (si * (si - 1)) / 2));

    __shared__ ushort A0[BT * 64], A1[BT * 64];   // persistent A (K-halves)
    __shared__ ushort B0[BT * 64], B1[BT * 64];   // streamed B (K-halves)
    __shared__ double rr[16];

    const int lane = tid & 63;
    const int wv   = tid >> 6;           // wave 0..7
    const int wr2  = wv >> 2;            // 0..1 -> row base *128
    const int wc4  = wv & 3;             // 0..3 -> col base *64

    const int srow = lane >> 3;          // 0..7 within 1KB chunk
    const int skb  = (lane & 7) * 16;    // 16B slot within 128B row

    const char* gAp = (const char*)(xb + (size_t)si * BT * DIM);
    const char* gBp = (const char*)(xb + (size_t)tj * BT * DIM);

    // A: both halves, 8 waves x 8 chunks (waves 0-3 -> A0, 4-7 -> A1)
#define STAGE_A()                                                             \
    {                                                                         \
        const int h_ = wv >> 2;                                               \
        char* dst_ = h_ ? (char*)A1 : (char*)A0;                              \
        _Pragma("unroll")                                                     \
        for (int c = 0; c < 8; ++c) {                                         \
            const int chunk = (wv & 3) * 8 + c;                               \
            const int row   = chunk * 8 + srow;                               \
            const size_t go = (size_t)row * 256 + h_ * 128                    \
                              + (skb ^ ((row & 7) << 4));                     \
            gload16(gAp + go, dst_ + chunk * 1024);                           \
        }                                                                     \
    }

    // B: one half, 8 waves x 4 chunks
#define STAGE_B(h, buf)                                                       \
    {                                                                         \
        char* dst_ = (char*)(buf);                                            \
        _Pragma("unroll")                                                     \
        for (int c = 0; c < 4; ++c) {                                         \
            const int chunk = wv * 4 + c;                                     \
            const int row   = chunk * 8 + srow;                               \
            const size_t go = (size_t)row * 256 + (h) * 128                   \
                              + (skb ^ ((row & 7) << 4));                     \
            gload16(gBp + go, dst_ + chunk * 1024);                           \
        }                                                                     \
    }

    f32x4 acc[8][4];
#define COMPUTE(dA, dB)                                                       \
    {                                                                         \
        _Pragma("unroll")                                                     \
        for (int ks = 0; ks < 2; ++ks) {                                      \
            const int kb = ks * 64 + (lane >> 4) * 16;                        \
            short8 af[8], bfr[4];                                             \
            _Pragma("unroll")                                                 \
            for (int m = 0; m < 8; ++m) {                                     \
                const int row = wr2 * 128 + m * 16 + (lane & 15);             \
                af[m] = *reinterpret_cast<const short8*>(                     \
                    (const char*)(dA) + row * 128 + (kb ^ ((row & 7) << 4))); \
            }                                                                 \
            _Pragma("unroll")                                                 \
            for (int n = 0; n < 4; ++n) {                                     \
                const int col = wc4 * 64 + n * 16 + (lane & 15);              \
                bfr[n] = *reinterpret_cast<const short8*>(                    \
                    (const char*)(dB) + col * 128 + (kb ^ ((col & 7) << 4))); \
            }                                                                 \
            _Pragma("unroll")                                                 \
            for (int m = 0; m < 8; ++m)                                       \
                _Pragma("unroll")                                             \
                for (int n = 0; n < 4; ++n)                                   \
                    acc[m][n] = __builtin_amdgcn_mfma_f32_16x16x32_bf16(      \
                        af[m], bfr[n], acc[m][n], 0, 0, 0);                   \
        }                                                                     \
    }

    // ---- prologue: A (both halves) + first pair's B half 0 ----
    STAGE_A();
    STAGE_B(0, B0);

    int   csi = si, ctj = tj;
    float s1t = 0.f, s2t = 0.f;

    for (int it = 0; it < pcnt; ++it) {
        __syncthreads();                 // A + B0(h0) landed (vmcnt drained)

        STAGE_B(1, B1);                  // h1 flies under h0 compute
#pragma unroll
        for (int m = 0; m < 8; ++m)
#pragma unroll
            for (int n = 0; n < 4; ++n) acc[m][n] = (f32x4){0.f, 0.f, 0.f, 0.f};
        COMPUTE(A0, B0);

        // next pair (row-major upper-tri walk)
        int nsi = csi, ntj = ctj + 1;
        if (ntj == NT2) { ++nsi; ntj = nsi; }
        const bool more  = (it + 1 < pcnt);
        const bool cross = more && (nsi != csi);

        __syncthreads();                 // B1 landed; all waves done with B0
        if (more && !cross) {
            gBp = (const char*)(xb + (size_t)ntj * BT * DIM);
            STAGE_B(0, B0);              // next pair h0 under this h1 compute
        }
        COMPUTE(A1, B1);

        // ---- epilogue for this pair (r7 dual-sum, weight folded) ----
        const float* sqA = sq + csi * BT + wr2 * 128 + (lane >> 4) * 4;
        const float* sqB = sq + ctj * BT + wc4 * 64 + (lane & 15);
        float nb[4];
#pragma unroll
        for (int n = 0; n < 4; ++n) nb[n] = sqB[n * 16];

        float s1a = 0.f, s1b = 0.f, s2a = 0.f, s2b = 0.f;
        const bool diag = (csi == ctj);
        if (!diag) {
#pragma unroll
            for (int m = 0; m < 8; ++m) {
                const float4 v = *reinterpret_cast<const float4*>(sqA + m * 16);
#pragma unroll
                for (int n = 0; n < 4; ++n) {
                    float d0 = fmaxf(fmaf(-2.f, acc[m][n][0], v.x + nb[n]), 0.f);
                    float d1 = fmaxf(fmaf(-2.f, acc[m][n][1], v.y + nb[n]), 0.f);
                    float d2 = fmaxf(fmaf(-2.f, acc[m][n][2], v.z + nb[n]), 0.f);
                    float d3 = fmaxf(fmaf(-2.f, acc[m][n][3], v.w + nb[n]), 0.f);
                    s1a += fsqrt(d0); s1b += fsqrt(d1);
                    s1a += fsqrt(d2); s1b += fsqrt(d3);
                    s2a += d0 + d2;   s2b += d1 + d3;
                }
            }
            s1t += 2.f * ((s1a + s1b));
            s2t += 2.f * ((s2a + s2b));
        } else {
#pragma unroll
            for (int m = 0; m < 8; ++m) {
                const float4 v = *reinterpret_cast<const float4*>(sqA + m * 16);
                const float nav[4] = {v.x, v.y, v.z, v.w};
#pragma unroll
                for (int n = 0; n < 4; ++n) {
                    const int col = wc4 * 64 + n * 16 + (lane & 15);
#pragma unroll
                    for (int r = 0; r < 4; ++r) {
                        const int row = wr2 * 128 + m * 16 + (lane >> 4) * 4 + r;
                        float d = fmaxf(fmaf(-2.f, acc[m][n][r], nav[r] + nb[n]), 0.f);
                        if (row == col) d = 0.f;   // exact-0 diagonal like ref
                        s1a += fsqrt(d);
                        s2a += d;
                    }
                }
            }
            s1t += s1a; s2t += s2a;
        }

        if (cross) {
            __syncthreads();             // all waves done reading A this pair
            gAp = (const char*)(xb + (size_t)nsi * BT * DIM);
            gBp = (const char*)(xb + (size_t)ntj * BT * DIM);
            STAGE_A();                   // restage A (row crossed)
            STAGE_B(0, B0);
        }
        csi = nsi; ctj = ntj;
    }

    // ---- block reduction: one shfl chain for the whole block ----
#pragma unroll
    for (int off = 1; off < 64; off <<= 1) {
        s1t += __shfl_xor(s1t, off);
        s2t += __shfl_xor(s2t, off);
    }
    if (lane == 0) { rr[wv] = (double)s1t; rr[8 + wv] = (double)s2t; }
    __syncthreads();
    if (tid == 0) {
        double t1 = 0.0, t2 = 0.0;
#pragma unroll
        for (int i = 0; i < 8; ++i) { t1 += rr[i]; t2 += rr[8 + i]; }
        partials[2 * b] = t1; partials[2 * b + 1] = t2;
    }
#undef STAGE_A
#undef STAGE_B
#undef COMPUTE
}

// ---------------- finalize (light, r7-style) ----------------
__global__ __launch_bounds__(256)
void ph_finalize(const double* __restrict__ partials, float* __restrict__ out)
{
    __shared__ double r1[256], r2[256];
    const int tid = threadIdx.x;
    double s1 = partials[2 * tid];       // NGBLK == 256: one entry per thread
    double s2 = partials[2 * tid + 1];
    r1[tid] = s1; r2[tid] = s2;
    __syncthreads();
    for (int off = 128; off > 0; off >>= 1) {
        if (tid < off) { r1[tid] += r1[tid + off]; r2[tid] += r2[tid + off]; }
        __syncthreads();
    }
    if (tid == 0) {
        const double M    = (double)NPTS * (double)NPTS;
        const double mean = r1[0] / M;
        double var = (r2[0] - r1[0] * r1[0] / M) / (M - 1.0);
        if (var < 0.0) var = 0.0;
        out[0] = (float)(sqrt(var) / (mean + 1e-8));
    }
}

// ---------------- fp32 fallback (only if ws too small) ----------------
#define LSTR 132
__global__ __launch_bounds__(256)
void ph_pair_kernel(const float* __restrict__ x, double* __restrict__ partials)
{
    const int bi  = blockIdx.y;
    const int bj  = blockIdx.x;
    const int tid = threadIdx.x;
    const int flat = bi * NTILES + bj;
    if (bj < bi) {
        if (tid == 0) { partials[2*flat] = 0.0; partials[2*flat+1] = 0.0; }
        return;
    }
    __shared__ __align__(16) float As[128 * LSTR];
    __shared__ __align__(16) float Bs[128 * LSTR];
    __shared__ float  nA[128];
    __shared__ float  nB[128];
    __shared__ double red1[256];
    __shared__ double red2[256];
    const float* Ab = x + (size_t)bi * 128 * DIM;
    const float* Bb = x + (size_t)bj * 128 * DIM;
#pragma unroll
    for (int it = 0; it < 16; ++it) {
        const int e   = (tid + it * 256) * 4;
        const int row = e >> 7;
        const int k   = e & 127;
        float4 va = *reinterpret_cast<const float4*>(Ab + e);
        As[(k+0)*LSTR + row] = va.x; As[(k+1)*LSTR + row] = va.y;
        As[(k+2)*LSTR + row] = va.z; As[(k+3)*LSTR + row] = va.w;
        float4 vb = *reinterpret_cast<const float4*>(Bb + e);
        Bs[(k+0)*LSTR + row] = vb.x; Bs[(k+1)*LSTR + row] = vb.y;
        Bs[(k+2)*LSTR + row] = vb.z; Bs[(k+3)*LSTR + row] = vb.w;
    }
    __syncthreads();
    if (tid < 128) {
        float s = 0.f;
#pragma unroll 8
        for (int k = 0; k < DIM; ++k) { float v = As[k*LSTR + tid]; s = fmaf(v, v, s); }
        nA[tid] = s;
    } else {
        const int r = tid - 128;
        float s = 0.f;
#pragma unroll 8
        for (int k = 0; k < DIM; ++k) { float v = Bs[k*LSTR + r]; s = fmaf(v, v, s); }
        nB[r] = s;
    }
    __syncthreads();
    const int tx = tid & 15, ty = tid >> 4;
    const int ra = ty * 8, cb = tx * 8;
    float acc[8][8];
#pragma unroll
    for (int r = 0; r < 8; ++r)
#pragma unroll
        for (int c = 0; c < 8; ++c) acc[r][c] = 0.f;
#pragma unroll 4
    for (int k = 0; k < DIM; ++k) {
        const float4 a0 = *reinterpret_cast<const float4*>(&As[k*LSTR + ra]);
        const float4 a1 = *reinterpret_cast<const float4*>(&As[k*LSTR + ra + 4]);
        const float4 b0 = *reinterpret_cast<const float4*>(&Bs[k*LSTR + cb]);
        const float4 b1 = *reinterpret_cast<const float4*>(&Bs[k*LSTR + cb + 4]);
        const float a[8] = {a0.x,a0.y,a0.z,a0.w,a1.x,a1.y,a1.z,a1.w};
        const float b[8] = {b0.x,b0.y,b0.z,b0.w,b1.x,b1.y,b1.z,b1.w};
#pragma unroll
        for (int r = 0; r < 8; ++r)
#pragma unroll
            for (int c = 0; c < 8; ++c)
                acc[r][c] = fmaf(a[r], b[c], acc[r][c]);
    }
    double s1 = 0.0, s2 = 0.0;
    const int gi0 = bi*128 + ra, gj0 = bj*128 + cb;
#pragma unroll
    for (int r = 0; r < 8; ++r) {
#pragma unroll
        for (int c = 0; c < 8; ++c) {
            float d2 = nA[ra+r] + nB[cb+c] - 2.0f * acc[r][c];
            d2 = fmaxf(d2, 0.0f);
            if (gi0 + r == gj0 + c) d2 = 0.0f;
            s1 += (double)sqrtf(d2);
            s2 += (double)d2;
        }
    }
    const double w = (bi == bj) ? 1.0 : 2.0;
    s1 *= w; s2 *= w;
    red1[tid] = s1; red2[tid] = s2;
    __syncthreads();
    for (int off = 128; off > 0; off >>= 1) {
        if (tid < off) { red1[tid] += red1[tid+off]; red2[tid] += red2[tid+off]; }
        __syncthreads();
    }
    if (tid == 0) { partials[2*flat] = red1[0]; partials[2*flat+1] = red2[0]; }
}

__global__ __launch_bounds__(256)
void ph_finalize_sq(const double* __restrict__ partials, float* __restrict__ out)
{
    __shared__ double r1[256], r2[256];
    const int tid = threadIdx.x;
    double s1 = 0.0, s2 = 0.0;
    for (int i = tid; i < NTOTSQ; i += 256) { s1 += partials[2*i]; s2 += partials[2*i+1]; }
    r1[tid] = s1; r2[tid] = s2;
    __syncthreads();
    for (int off = 128; off > 0; off >>= 1) {
        if (tid < off) { r1[tid] += r1[tid+off]; r2[tid] += r2[tid+off]; }
        __syncthreads();
    }
    if (tid == 0) {
        const double M    = (double)NPTS * (double)NPTS;
        const double mean = r1[0] / M;
        double var = (r2[0] - r1[0]*r1[0]/M) / (M - 1.0);
        if (var < 0.0) var = 0.0;
        out[0] = (float)(sqrt(var) / (mean + 1e-8));
    }
}

extern "C" void kernel_launch(void* const* d_in, const int* in_sizes, int n_in,
                              void* d_out, int out_size, void* d_ws, size_t ws_size,
                              hipStream_t stream)
{
    const float* x = (const float*)d_in[0];   // [8192, 128] fp32
    float* out     = (float*)d_out;

    // ws layout: xb bf16 (2MB) | sq (32KB) | partials (256*2*8)
    const size_t XB_OFF = 0;
    const size_t SQ_OFF = (size_t)NPTS * DIM * sizeof(ushort);   // 2 MB
    const size_t PT_OFF = SQ_OFF + NPTS * sizeof(float);
    const size_t NEEDED = PT_OFF + (size_t)NGBLK * 2 * sizeof(double);

    if (ws_size >= NEEDED) {
        ushort* xb       = (ushort*)((char*)d_ws + XB_OFF);
        float*  sq       = (float*) ((char*)d_ws + SQ_OFF);
        double* partials = (double*)((char*)d_ws + PT_OFF);

        ph_prep<<<NPREP, 256, 0, stream>>>(x, xb, sq);
        ph_gram<<<NGBLK, 512, 0, stream>>>(xb, sq, partials);
        ph_finalize<<<1, 256, 0, stream>>>(partials, out);
    } else {
        double* partials = (double*)d_ws;
        ph_pair_kernel<<<dim3(NTILES, NTILES), 256, 0, stream>>>(x, partials);
        ph_finalize_sq<<<1, 256, 0, stream>>>(partials, out);
    }
}

// Round 15
// 33.662 us; speedup vs baseline: 3.2099x; 1.1009x over previous
//
#include <hip/hip_runtime.h>
#include <hip/hip_bf16.h>
#include <math.h>

// PersistentHomology: out = std(dist, ddof=1) / (mean(dist) + 1e-8) over the
// 8192x8192 Euclidean distance matrix of 8192 fp32 points, D=128.
// S1 = sum(dist), S2 = sum(dist^2); symmetry -> upper-triangle tiles only.
// Gram via pure-bf16 MFMA (random +-3e-3 per-dist error averages out; final
// error ~1e-4 << 1.27e-3 threshold). Norms exact fp32.
// Round 15: EXACT replicate of round-7's 33.7us kernel (reproducibility A/B —
// all post-r7 structural variants landed 35.5-39.7; need to know if 33.7 is
// real or noise before declaring the plateau).

#define NPTS   8192
#define DIM    128
#define BT     256                            // block tile
#define NT2    (NPTS / BT)                    // 32 tiles per side
#define NBLK   (NT2 * (NT2 + 1) / 2)          // 528 upper-tri blocks
#define NTILES (NPTS / 128)                   // for fp32 fallback path
#define NTOTSQ (NTILES * NTILES)

typedef __attribute__((ext_vector_type(8))) short short8;   // 8 bf16
typedef __attribute__((ext_vector_type(4))) float f32x4;    // MFMA accumulator

typedef const __attribute__((address_space(1))) void* gas_ptr;
typedef __attribute__((address_space(3))) void* las_ptr;

__device__ __forceinline__ void gload16(const void* g, void* l) {
    // DMA 16B/lane global->LDS; LDS dest = wave-uniform base + lane*16
    __builtin_amdgcn_global_load_lds((gas_ptr)g, (las_ptr)l, 16, 0, 0);
}

__device__ __forceinline__ float fsqrt(float x) {
    return __builtin_amdgcn_sqrtf(x);        // v_sqrt_f32, ~1 ulp
}

// ---------------- prep: fp32 -> bf16 + fp32 squared norms (fused) ----------------
__global__ __launch_bounds__(256)
void ph_prep(const float* __restrict__ x, ushort* __restrict__ xb,
             float* __restrict__ sq)
{
    const int tid = threadIdx.x;
    const int row = blockIdx.x * 32 + (tid >> 3);
    const int seg = tid & 7;                       // 16 elems per thread
    const float4* p = reinterpret_cast<const float4*>(x + (size_t)row * DIM + seg * 16);
    float v[16];
    {
        float4 a = p[0], b = p[1], c = p[2], d = p[3];
        v[0]=a.x; v[1]=a.y; v[2]=a.z; v[3]=a.w;  v[4]=b.x; v[5]=b.y; v[6]=b.z; v[7]=b.w;
        v[8]=c.x; v[9]=c.y; v[10]=c.z; v[11]=c.w; v[12]=d.x; v[13]=d.y; v[14]=d.z; v[15]=d.w;
    }
    float s = 0.f;
    ushort h[16];
#pragma unroll
    for (int j = 0; j < 16; ++j) {
        __hip_bfloat16 hb = __float2bfloat16(v[j]);
        h[j] = *reinterpret_cast<ushort*>(&hb);
        s = fmaf(v[j], v[j], s);
    }
    short8 o0, o1;
#pragma unroll
    for (int j = 0; j < 8; ++j) { o0[j] = (short)h[j]; o1[j] = (short)h[j+8]; }
    short8* dst = reinterpret_cast<short8*>(xb + (size_t)row * DIM + seg * 16);
    dst[0] = o0; dst[1] = o1;
    s += __shfl_xor(s, 1); s += __shfl_xor(s, 2); s += __shfl_xor(s, 4);
    if (seg == 0) sq[row] = s;
}

// ---------------- main: 256^2-tile, 8-wave, double-buffered bf16 MFMA Gram ----
// LDS half-buffers: 256 rows x 128B, swizzled: phys = row*128 + (kb ^ ((row&7)<<4))
// Stage writes linear (gload_lds); inverse swizzle applied on the GLOBAL source.
__global__ __launch_bounds__(512)
void ph_gram(const ushort* __restrict__ xb, const float* __restrict__ sq,
             double* __restrict__ partials)
{
    const int f   = blockIdx.x;          // 0..NBLK-1
    const int tid = threadIdx.x;

    // decode flat -> (bi, bj), bi <= bj ; T(r) = r*32 - r*(r-1)/2
    int bi = (int)((65.0f - fsqrt((float)(4225 - 8 * f))) * 0.5f);
    while ((bi + 1) * 32 - ((bi + 1) * bi) / 2 <= f) ++bi;
    while (bi * 32 - (bi * (bi - 1)) / 2 > f) --bi;
    const int bj = bi + (f - (bi * 32 - (bi * (bi - 1)) / 2));

    __shared__ ushort A0[BT * 64], B0[BT * 64];   // 32 KB each (K-half 0)
    __shared__ ushort A1[BT * 64], B1[BT * 64];   // 32 KB each (K-half 1)
    __shared__ double rr[16];

    const int lane = tid & 63;
    const int wv   = tid >> 6;           // wave 0..7
    const int wr2  = wv >> 2;            // 0..1 -> row base *128
    const int wc4  = wv & 3;             // 0..3 -> col base *64

    const char* gA = (const char*)(xb + (size_t)bi * BT * DIM);
    const char* gB = (const char*)(xb + (size_t)bj * BT * DIM);

    // staging: waves 0-3 stage A (32 chunks of 1KB), waves 4-7 stage B
    const bool  stA  = wv < 4;
    const char* gsrc = stA ? gA : gB;
    const int   cb0  = (wv & 3) * 8;           // 8 chunks per wave
    const int   srow = lane >> 3;              // 0..7 within chunk
    const int   skb  = (lane & 7) * 16;        // 16B slot within 128B row

#define STAGE(h, dA, dB)                                                      \
    {                                                                         \
        char* dst_ = stA ? (char*)(dA) : (char*)(dB);                         \
        _Pragma("unroll")                                                     \
        for (int c = 0; c < 8; ++c) {                                         \
            const int chunk = cb0 + c;                                        \
            const int row   = chunk * 8 + srow;                               \
            const size_t go = (size_t)row * 256 + (h) * 128                   \
                              + (skb ^ ((row & 7) << 4));                     \
            gload16(gsrc + go, dst_ + chunk * 1024);                          \
        }                                                                     \
    }

    f32x4 acc[8][4];
#pragma unroll
    for (int m = 0; m < 8; ++m)
#pragma unroll
        for (int n = 0; n < 4; ++n) acc[m][n] = (f32x4){0.f, 0.f, 0.f, 0.f};

#define COMPUTE(dA, dB)                                                       \
    {                                                                         \
        _Pragma("unroll")                                                     \
        for (int ks = 0; ks < 2; ++ks) {                                      \
            const int kb = ks * 64 + (lane >> 4) * 16;                        \
            short8 af[8], bfr[4];                                             \
            _Pragma("unroll")                                                 \
            for (int m = 0; m < 8; ++m) {                                     \
                const int row = wr2 * 128 + m * 16 + (lane & 15);             \
                af[m] = *reinterpret_cast<const short8*>(                     \
                    (const char*)(dA) + row * 128 + (kb ^ ((row & 7) << 4))); \
            }                                                                 \
            _Pragma("unroll")                                                 \
            for (int n = 0; n < 4; ++n) {                                     \
                const int col = wc4 * 64 + n * 16 + (lane & 15);              \
                bfr[n] = *reinterpret_cast<const short8*>(                    \
                    (const char*)(dB) + col * 128 + (kb ^ ((col & 7) << 4))); \
            }                                                                 \
            _Pragma("unroll")                                                 \
            for (int m = 0; m < 8; ++m)                                       \
                _Pragma("unroll")                                             \
                for (int n = 0; n < 4; ++n)                                   \
                    acc[m][n] = __builtin_amdgcn_mfma_f32_16x16x32_bf16(      \
                        af[m], bfr[n], acc[m][n], 0, 0, 0);                   \
        }                                                                     \
    }

    STAGE(0, A0, B0);
    __syncthreads();      // half 0 ready (drains vmcnt)
    STAGE(1, A1, B1);     // half 1 in flight under half-0 compute
    COMPUTE(A0, B0);
    __syncthreads();      // half 1 ready (loads already landed under compute)
    COMPUTE(A1, B1);

    // ---- epilogue: distances, fp32 dual accumulators, wave-uniform diag split --
    const float* sqA = sq + bi * BT + wr2 * 128 + (lane >> 4) * 4;
    const float* sqB = sq + bj * BT + wc4 * 64 + (lane & 15);
    float nB_[4];
#pragma unroll
    for (int n = 0; n < 4; ++n) nB_[n] = sqB[n * 16];

    float s1a = 0.f, s1b = 0.f, s2a = 0.f, s2b = 0.f;
    const bool diag = (bi == bj);
    if (!diag) {
#pragma unroll
        for (int m = 0; m < 8; ++m) {
            const float4 na = *reinterpret_cast<const float4*>(sqA + m * 16);
#pragma unroll
            for (int n = 0; n < 4; ++n) {
                float d0 = fmaxf(fmaf(-2.f, acc[m][n][0], na.x + nB_[n]), 0.f);
                float d1 = fmaxf(fmaf(-2.f, acc[m][n][1], na.y + nB_[n]), 0.f);
                float d2 = fmaxf(fmaf(-2.f, acc[m][n][2], na.z + nB_[n]), 0.f);
                float d3 = fmaxf(fmaf(-2.f, acc[m][n][3], na.w + nB_[n]), 0.f);
                s1a += fsqrt(d0); s1b += fsqrt(d1);
                s1a += fsqrt(d2); s1b += fsqrt(d3);
                s2a += d0 + d2;     s2b += d1 + d3;
            }
        }
    } else {
#pragma unroll
        for (int m = 0; m < 8; ++m) {
            const float4 na = *reinterpret_cast<const float4*>(sqA + m * 16);
            const float nav[4] = {na.x, na.y, na.z, na.w};
#pragma unroll
            for (int n = 0; n < 4; ++n) {
                const int col = wc4 * 64 + n * 16 + (lane & 15);
#pragma unroll
                for (int r = 0; r < 4; ++r) {
                    const int row = wr2 * 128 + m * 16 + (lane >> 4) * 4 + r;
                    float d = fmaxf(fmaf(-2.f, acc[m][n][r], nav[r] + nB_[n]), 0.f);
                    if (row == col) d = 0.f;      // exact-0 diagonal like ref
                    s1a += fsqrt(d);
                    s2a += d;
                }
            }
        }
    }
    float s1 = s1a + s1b, s2 = s2a + s2b;
#pragma unroll
    for (int off = 1; off < 64; off <<= 1) {
        s1 += __shfl_xor(s1, off);
        s2 += __shfl_xor(s2, off);
    }
    const double w = diag ? 1.0 : 2.0;
    if (lane == 0) { rr[wv] = (double)s1 * w; rr[8 + wv] = (double)s2 * w; }
    __syncthreads();
    if (tid == 0) {
        double t1 = 0.0, t2 = 0.0;
#pragma unroll
        for (int i = 0; i < 8; ++i) { t1 += rr[i]; t2 += rr[8 + i]; }
        partials[2*f] = t1; partials[2*f + 1] = t2;
    }
#undef STAGE
#undef COMPUTE
}

// ---------------- finalize ----------------
__global__ __launch_bounds__(256)
void ph_finalize(const double* __restrict__ partials, float* __restrict__ out)
{
    __shared__ double r1[256], r2[256];
    const int tid = threadIdx.x;
    double s1 = 0.0, s2 = 0.0;
    for (int i = tid; i < NBLK; i += 256) { s1 += partials[2*i]; s2 += partials[2*i+1]; }
    r1[tid] = s1; r2[tid] = s2;
    __syncthreads();
    for (int off = 128; off > 0; off >>= 1) {
        if (tid < off) { r1[tid] += r1[tid+off]; r2[tid] += r2[tid+off]; }
        __syncthreads();
    }
    if (tid == 0) {
        const double M    = (double)NPTS * (double)NPTS;
        const double mean = r1[0] / M;
        double var = (r2[0] - r1[0]*r1[0]/M) / (M - 1.0);
        if (var < 0.0) var = 0.0;
        out[0] = (float)(sqrt(var) / (mean + 1e-8));
    }
}

// ---------------- fp32 fallback (only if ws too small) ----------------
#define LSTR 132
__global__ __launch_bounds__(256)
void ph_pair_kernel(const float* __restrict__ x, double* __restrict__ partials)
{
    const int bi  = blockIdx.y;
    const int bj  = blockIdx.x;
    const int tid = threadIdx.x;
    const int flat = bi * NTILES + bj;
    if (bj < bi) {
        if (tid == 0) { partials[2*flat] = 0.0; partials[2*flat+1] = 0.0; }
        return;
    }
    __shared__ __align__(16) float As[128 * LSTR];
    __shared__ __align__(16) float Bs[128 * LSTR];
    __shared__ float  nA[128];
    __shared__ float  nB[128];
    __shared__ double red1[256];
    __shared__ double red2[256];
    const float* Ab = x + (size_t)bi * 128 * DIM;
    const float* Bb = x + (size_t)bj * 128 * DIM;
#pragma unroll
    for (int it = 0; it < 16; ++it) {
        const int e   = (tid + it * 256) * 4;
        const int row = e >> 7;
        const int k   = e & 127;
        float4 va = *reinterpret_cast<const float4*>(Ab + e);
        As[(k+0)*LSTR + row] = va.x; As[(k+1)*LSTR + row] = va.y;
        As[(k+2)*LSTR + row] = va.z; As[(k+3)*LSTR + row] = va.w;
        float4 vb = *reinterpret_cast<const float4*>(Bb + e);
        Bs[(k+0)*LSTR + row] = vb.x; Bs[(k+1)*LSTR + row] = vb.y;
        Bs[(k+2)*LSTR + row] = vb.z; Bs[(k+3)*LSTR + row] = vb.w;
    }
    __syncthreads();
    if (tid < 128) {
        float s = 0.f;
#pragma unroll 8
        for (int k = 0; k < DIM; ++k) { float v = As[k*LSTR + tid]; s = fmaf(v, v, s); }
        nA[tid] = s;
    } else {
        const int r = tid - 128;
        float s = 0.f;
#pragma unroll 8
        for (int k = 0; k < DIM; ++k) { float v = Bs[k*LSTR + r]; s = fmaf(v, v, s); }
        nB[r] = s;
    }
    __syncthreads();
    const int tx = tid & 15, ty = tid >> 4;
    const int ra = ty * 8, cb = tx * 8;
    float acc[8][8];
#pragma unroll
    for (int r = 0; r < 8; ++r)
#pragma unroll
        for (int c = 0; c < 8; ++c) acc[r][c] = 0.f;
#pragma unroll 4
    for (int k = 0; k < DIM; ++k) {
        const float4 a0 = *reinterpret_cast<const float4*>(&As[k*LSTR + ra]);
        const float4 a1 = *reinterpret_cast<const float4*>(&As[k*LSTR + ra + 4]);
        const float4 b0 = *reinterpret_cast<const float4*>(&Bs[k*LSTR + cb]);
        const float4 b1 = *reinterpret_cast<const float4*>(&Bs[k*LSTR + cb + 4]);
        const float a[8] = {a0.x,a0.y,a0.z,a0.w,a1.x,a1.y,a1.z,a1.w};
        const float b[8] = {b0.x,b0.y,b0.z,b0.w,b1.x,b1.y,b1.z,b1.w};
#pragma unroll
        for (int r = 0; r < 8; ++r)
#pragma unroll
            for (int c = 0; c < 8; ++c)
                acc[r][c] = fmaf(a[r], b[c], acc[r][c]);
    }
    double s1 = 0.0, s2 = 0.0;
    const int gi0 = bi*128 + ra, gj0 = bj*128 + cb;
#pragma unroll
    for (int r = 0; r < 8; ++r) {
#pragma unroll
        for (int c = 0; c < 8; ++c) {
            float d2 = nA[ra+r] + nB[cb+c] - 2.0f * acc[r][c];
            d2 = fmaxf(d2, 0.0f);
            if (gi0 + r == gj0 + c) d2 = 0.0f;
            s1 += (double)sqrtf(d2);
            s2 += (double)d2;
        }
    }
    const double w = (bi == bj) ? 1.0 : 2.0;
    s1 *= w; s2 *= w;
    red1[tid] = s1; red2[tid] = s2;
    __syncthreads();
    for (int off = 128; off > 0; off >>= 1) {
        if (tid < off) { red1[tid] += red1[tid+off]; red2[tid] += red2[tid+off]; }
        __syncthreads();
    }
    if (tid == 0) { partials[2*flat] = red1[0]; partials[2*flat+1] = red2[0]; }
}

__global__ __launch_bounds__(256)
void ph_finalize_sq(const double* __restrict__ partials, float* __restrict__ out)
{
    __shared__ double r1[256], r2[256];
    const int tid = threadIdx.x;
    double s1 = 0.0, s2 = 0.0;
    for (int i = tid; i < NTOTSQ; i += 256) { s1 += partials[2*i]; s2 += partials[2*i+1]; }
    r1[tid] = s1; r2[tid] = s2;
    __syncthreads();
    for (int off = 128; off > 0; off >>= 1) {
        if (tid < off) { r1[tid] += r1[tid+off]; r2[tid] += r2[tid+off]; }
        __syncthreads();
    }
    if (tid == 0) {
        const double M    = (double)NPTS * (double)NPTS;
        const double mean = r1[0] / M;
        double var = (r2[0] - r1[0]*r1[0]/M) / (M - 1.0);
        if (var < 0.0) var = 0.0;
        out[0] = (float)(sqrt(var) / (mean + 1e-8));
    }
}

extern "C" void kernel_launch(void* const* d_in, const int* in_sizes, int n_in,
                              void* d_out, int out_size, void* d_ws, size_t ws_size,
                              hipStream_t stream)
{
    const float* x = (const float*)d_in[0];   // [8192, 128] fp32
    float* out     = (float*)d_out;

    // ws layout: xb bf16 (2MB) | sq (32KB) | partials
    const size_t XB_OFF = 0;
    const size_t SQ_OFF = (size_t)NPTS * DIM * sizeof(ushort);   // 2 MB
    const size_t PT_OFF = SQ_OFF + NPTS * sizeof(float);
    const size_t NEEDED = PT_OFF + (size_t)NTOTSQ * 2 * sizeof(double);

    if (ws_size >= NEEDED) {
        ushort* xb       = (ushort*)((char*)d_ws + XB_OFF);
        float*  sq       = (float*) ((char*)d_ws + SQ_OFF);
        double* partials = (double*)((char*)d_ws + PT_OFF);

        ph_prep<<<NPTS / 32, 256, 0, stream>>>(x, xb, sq);
        ph_gram<<<NBLK, 512, 0, stream>>>(xb, sq, partials);
        ph_finalize<<<1, 256, 0, stream>>>(partials, out);
    } else {
        double* partials = (double*)d_ws;
        ph_pair_kernel<<<dim3(NTILES, NTILES), 256, 0, stream>>>(x, partials);
        ph_finalize_sq<<<1, 256, 0, stream>>>(partials, out);
    }
}